// Round 9
// baseline (145.670 us; speedup 1.0000x reference)
//
#include <hip/hip_runtime.h>

#define NPIX 4194304   // 64*256*256 per image
#define BATCH 4
#define MINK 1024ULL
#define NBINS 4096
#define G1 512         // blocks per image in k_reduce (2048 total)
#define TOT (G1 * BATCH)
#define HG 256         // blocks per image in k_tail hist path

typedef unsigned long long u64;
typedef int vint4 __attribute__((ext_vector_type(4)));
typedef float vflt4 __attribute__((ext_vector_type(4)));

__device__ __forceinline__ float pix_loss(float v0, float v1, float v2, int t) {
    float m = fmaxf(fmaxf(v0, v1), v2);
    float lse = m + __logf(__expf(v0 - m) + __expf(v1 - m) + __expf(v2 - m));
    float xt = (t == 0) ? v0 : ((t == 1) ? v1 : v2);
    return lse - xt;
}

// helper: reduce one image's G1 partial slots across a 256-thread block.
// Totals broadcast to ALL threads via LDS.
__device__ __forceinline__ void reduce_image(const float* __restrict__ pfs,
                                             const float* __restrict__ pbs,
                                             const unsigned* __restrict__ pfc,
                                             int b2, int tid,
                                             double* __restrict__ sda,
                                             double* __restrict__ sdb,
                                             unsigned* __restrict__ su,
                                             double& tfs, double& tbs, u64& tfc) {
    double fs = 0.0, bs = 0.0;
    unsigned fc = 0;
    if (tid < G1 / 4) {
        const float4 f4 = ((const float4*)pfs)[b2 * (G1 / 4) + tid];
        const float4 b4 = ((const float4*)pbs)[b2 * (G1 / 4) + tid];
        const uint4 c4 = ((const uint4*)pfc)[b2 * (G1 / 4) + tid];
        fs = (double)f4.x + (double)f4.y + (double)f4.z + (double)f4.w;
        bs = (double)b4.x + (double)b4.y + (double)b4.z + (double)b4.w;
        fc = c4.x + c4.y + c4.z + c4.w;
    }
#pragma unroll
    for (int off = 32; off > 0; off >>= 1) {
        fs += __shfl_down(fs, off);
        bs += __shfl_down(bs, off);
        fc += __shfl_down(fc, off);
    }
    const int wid = tid >> 6;
    if ((tid & 63) == 0) { sda[wid] = fs; sdb[wid] = bs; su[wid] = fc; }
    __syncthreads();
    tfs = sda[0] + sda[1] + sda[2] + sda[3];
    tbs = sdb[0] + sdb[1] + sdb[2] + sdb[3];
    tfc = (u64)su[0] + su[1] + su[2] + su[3];
    __syncthreads();
}

// K1: streaming reduce (NT loads, unroll-2 for deeper MLP) + last-block
// finalize. Counter is wrap-safe: exactly TOT increments per call, test via
// (old & (TOT-1)) == TOT-1, so no reset needed (2^32 % TOT == 0).
__global__ __launch_bounds__(256) void k_reduce(const float* __restrict__ x,
                                                const int* __restrict__ tg,
                                                float* __restrict__ pfs,
                                                float* __restrict__ pbs,
                                                unsigned* __restrict__ pfc,
                                                uint4* __restrict__ histz,
                                                unsigned* __restrict__ flags,
                                                float* __restrict__ out,
                                                int have_hist) {
    const int b = blockIdx.y;
    if (b == 0 && blockIdx.x < 32) {
        if (have_hist) histz[blockIdx.x * 256 + threadIdx.x] = make_uint4(0u, 0u, 0u, 0u);
        if (blockIdx.x == 0 && threadIdx.x == 0) flags[1] = 0u;   // k_tail hist done-counter
    }
    const float* xb = x + (size_t)b * 3 * NPIX;
    const int* tb = tg + (size_t)b * NPIX;
    float fs = 0.f, bs = 0.f;
    int fc = 0;
    const int base = (blockIdx.x * 256 + threadIdx.x) * 4;
    const int stride = G1 * 256 * 4;  // pixels per grid sweep
#pragma unroll
    for (int it = 0; it < NPIX / stride; it += 2) {
        const int i0 = it * stride + base;
        const int i1 = i0 + stride;
        const vflt4 a0 = __builtin_nontemporal_load((const vflt4*)(xb + i0));
        const vflt4 c0 = __builtin_nontemporal_load((const vflt4*)(xb + NPIX + i0));
        const vflt4 d0 = __builtin_nontemporal_load((const vflt4*)(xb + 2 * NPIX + i0));
        const vint4 t0 = __builtin_nontemporal_load((const vint4*)(tb + i0));
        const vflt4 a1 = __builtin_nontemporal_load((const vflt4*)(xb + i1));
        const vflt4 c1 = __builtin_nontemporal_load((const vflt4*)(xb + NPIX + i1));
        const vflt4 d1 = __builtin_nontemporal_load((const vflt4*)(xb + 2 * NPIX + i1));
        const vint4 t1 = __builtin_nontemporal_load((const vint4*)(tb + i1));
        float l;
#pragma unroll
        for (int j = 0; j < 4; ++j) {
            l = pix_loss(a0[j], c0[j], d0[j], t0[j]);
            if (t0[j] > 0) { fs += l; fc++; } else bs += l;
        }
#pragma unroll
        for (int j = 0; j < 4; ++j) {
            l = pix_loss(a1[j], c1[j], d1[j], t1[j]);
            if (t1[j] > 0) { fs += l; fc++; } else bs += l;
        }
    }
#pragma unroll
    for (int off = 32; off > 0; off >>= 1) {
        fs += __shfl_down(fs, off);
        bs += __shfl_down(bs, off);
        fc += __shfl_down(fc, off);
    }
    __shared__ float sfs[4], sbs[4];
    __shared__ int sfc[4];
    const int wid = threadIdx.x >> 6;
    if ((threadIdx.x & 63) == 0) { sfs[wid] = fs; sbs[wid] = bs; sfc[wid] = fc; }
    __syncthreads();
    __shared__ int lastf;
    if (threadIdx.x == 0) {
        const int slot = b * G1 + blockIdx.x;
        pfs[slot] = sfs[0] + sfs[1] + sfs[2] + sfs[3];
        pbs[slot] = sbs[0] + sbs[1] + sbs[2] + sbs[3];
        pfc[slot] = (unsigned)(sfc[0] + sfc[1] + sfc[2] + sfc[3]);
        __threadfence();                                   // release partials (device scope)
        unsigned old = atomicAdd(&flags[16], 1u);          // separate cache line
        lastf = ((old & (unsigned)(TOT - 1)) == (unsigned)(TOT - 1)) ? 1 : 0;
    }
    __syncthreads();
    if (!lastf) return;
    __threadfence();                                       // acquire (all threads)

    __shared__ double sda[4], sdb[4];
    __shared__ unsigned su[4];
    double acc = 0.0;
    unsigned mask = 0u;
    for (int b2 = 0; b2 < BATCH; ++b2) {
        double tfs, tbs; u64 tfc;
        reduce_image(pfs, pbs, pfc, b2, threadIdx.x, sda, sdb, su, tfs, tbs, tfc);
        const u64 bg = (u64)NPIX - tfc;
        const u64 mk = tfc > MINK ? tfc : MINK;
        const u64 k = bg < mk ? bg : mk;
        if (k < bg && have_hist) mask |= (1u << b2);
        const double fg_term = (tfc > 0) ? tfs / (double)tfc : 0.0;
        const u64 kd = k > 1 ? k : 1;
        const double bg_term = (bg > 0) ? tbs / (double)kd : 0.0;  // valid iff k>=bg (or !have_hist)
        acc += fg_term + bg_term;
    }
    if (threadIdx.x == 0) {
        flags[0] = mask;
        if (mask == 0u) out[0] = (float)(acc / (double)BATCH);
    }
}

// K2: hist fallback only. On this data flags[0]==0 -> every block exits after
// one load (cost ~ launch overhead only).
__global__ __launch_bounds__(256) void k_tail(const float* __restrict__ pfs,
                                              const float* __restrict__ pbs,
                                              const unsigned* __restrict__ pfc,
                                              const float* __restrict__ x,
                                              const int* __restrict__ tg,
                                              unsigned* __restrict__ hist_cnt,
                                              float* __restrict__ hist_sum,
                                              unsigned* __restrict__ flags,
                                              float* __restrict__ out) {
    const unsigned need = flags[0];
    if (need == 0u) return;
    const int b = blockIdx.y;
    const int tid = threadIdx.x;
    if (!(need & (1u << b))) return;

    __shared__ unsigned hc[NBINS];
    __shared__ float hs[NBINS];
    for (int i = tid; i < NBINS; i += 256) { hc[i] = 0u; hs[i] = 0.f; }
    __syncthreads();
    {
        const float* xb = x + (size_t)b * 3 * NPIX;
        const int* tb = tg + (size_t)b * NPIX;
        const int stride = HG * 256 * 4;
        for (int i = (blockIdx.x * 256 + tid) * 4; i < NPIX; i += stride) {
            const float4 a = *(const float4*)(xb + i);
            const float4 c = *(const float4*)(xb + NPIX + i);
            const float4 d = *(const float4*)(xb + 2 * NPIX + i);
            const int4 t4 = *(const int4*)(tb + i);
            float v[4][3] = {{a.x, c.x, d.x}, {a.y, c.y, d.y}, {a.z, c.z, d.z}, {a.w, c.w, d.w}};
            int tt[4] = {t4.x, t4.y, t4.z, t4.w};
#pragma unroll
            for (int j = 0; j < 4; ++j) {
                if (tt[j] == 0) {
                    float l = fmaxf(pix_loss(v[j][0], v[j][1], v[j][2], tt[j]), 0.f);
                    unsigned bin = __float_as_uint(l) >> 20;  // monotone for x>=0
                    atomicAdd(&hc[bin], 1u);
                    atomicAdd(&hs[bin], l);
                }
            }
        }
    }
    __syncthreads();
    for (int i = tid; i < NBINS; i += 256) {
        if (hc[i]) {
            atomicAdd(&hist_cnt[(size_t)b * NBINS + i], hc[i]);
            atomicAdd(&hist_sum[(size_t)b * NBINS + i], hs[i]);
        }
    }

    const int nneed = __popc(need);
    __threadfence();
    __syncthreads();
    __shared__ int is_last;
    if (tid == 0) {
        unsigned v = atomicAdd(&flags[1], 1u);
        is_last = (v == (unsigned)(HG * nneed) - 1u) ? 1 : 0;
    }
    __syncthreads();
    if (!is_last) return;
    __threadfence();

    __shared__ double sda[4], sdb[4];
    __shared__ unsigned su[4];
    double acc = 0.0;
    for (int b2 = 0; b2 < BATCH; ++b2) {
        double tfs, tbs; u64 tfc;
        reduce_image(pfs, pbs, pfc, b2, tid, sda, sdb, su, tfs, tbs, tfc);
        const u64 bg = (u64)NPIX - tfc;
        const u64 mk = tfc > MINK ? tfc : MINK;
        const u64 k = bg < mk ? bg : mk;
        double bg_sel = tbs;
        if (need & (1u << b2)) {
            for (int i = tid; i < NBINS; i += 256) {
                hc[i] = __hip_atomic_load(&hist_cnt[(size_t)b2 * NBINS + i],
                                          __ATOMIC_ACQUIRE, __HIP_MEMORY_SCOPE_AGENT);
                hs[i] = __hip_atomic_load(&hist_sum[(size_t)b2 * NBINS + i],
                                          __ATOMIC_ACQUIRE, __HIP_MEMORY_SCOPE_AGENT);
            }
            __syncthreads();
            if (tid == 0) {
                u64 cnt = 0; double s = 0.0, topk = 0.0;
                for (int i = NBINS - 1; i >= 0; --i) {
                    unsigned c = hc[i];
                    if (cnt + c >= k) {
                        double edge = (double)__uint_as_float(((unsigned)i) << 20);
                        topk = s + (double)(k - cnt) * edge;
                        break;
                    }
                    cnt += c;
                    s += (double)hs[i];
                }
                sda[0] = topk;
            }
            __syncthreads();
            bg_sel = sda[0];
            __syncthreads();
        }
        const double fg_term = (tfc > 0) ? tfs / (double)tfc : 0.0;
        const u64 kd = k > 1 ? k : 1;
        const double bg_term = (bg > 0) ? bg_sel / (double)kd : 0.0;
        acc += fg_term + bg_term;
    }
    if (tid == 0) out[0] = (float)(acc / (double)BATCH);
}

extern "C" void kernel_launch(void* const* d_in, const int* in_sizes, int n_in,
                              void* d_out, int out_size, void* d_ws, size_t ws_size,
                              hipStream_t stream) {
    const float* x = (const float*)d_in[0];
    const int* tg = (const int*)d_in[1];
    float* out = (float*)d_out;

    char* ws = (char*)d_ws;
    float* pfs = (float*)ws;                                   // 8 KB used
    float* pbs = (float*)(ws + 16384);                         // 8 KB used
    unsigned* pfc = (unsigned*)(ws + 32768);                   // 8 KB used
    unsigned* flags = (unsigned*)(ws + 49152);                 // 128 B (flags[16] on its own line)
    unsigned* hist_cnt = (unsigned*)(ws + 49280);              // 64 KB
    float* hist_sum = (float*)(ws + 49280 + (size_t)BATCH * NBINS * 4);  // 64 KB
    uint4* histz = (uint4*)(ws + 49280);                       // cnt+sum contiguous: 8192 uint4
    const size_t need_ws = 49280 + (size_t)BATCH * NBINS * 8;
    const int have_hist = (ws_size >= need_ws) ? 1 : 0;

    dim3 block(256);
    dim3 grid1(G1, BATCH);
    k_reduce<<<grid1, block, 0, stream>>>(x, tg, pfs, pbs, pfc, histz, flags, out, have_hist);
    if (have_hist) {
        dim3 grid2(HG, BATCH);
        k_tail<<<grid2, block, 0, stream>>>(pfs, pbs, pfc, x, tg,
                                            hist_cnt, hist_sum, flags, out);
    }
}

// Round 10
// 50.898 us; speedup vs baseline: 2.8620x; 2.8620x over previous
//
#include <hip/hip_runtime.h>

#define NPIX 4194304   // 64*256*256 per image
#define BATCH 4
#define MINK 1024ULL
#define NBINS 4096
#define G1 512         // blocks per image in k_reduce (2048 total = one full occupancy generation)
#define HG 256         // blocks per image in k_tail hist path

typedef unsigned long long u64;
typedef int vint4 __attribute__((ext_vector_type(4)));
typedef float vflt4 __attribute__((ext_vector_type(4)));

__device__ __forceinline__ float pix_loss(float v0, float v1, float v2, int t) {
    float m = fmaxf(fmaxf(v0, v1), v2);
    float lse = m + __logf(__expf(v0 - m) + __expf(v1 - m) + __expf(v2 - m));
    float xt = (t == 0) ? v0 : ((t == 1) ? v1 : v2);
    return lse - xt;
}

// K1: per-block partials via PLAIN STORES to unique slots — zero atomics,
// zero cross-call state. NT loads (no cache allocate; harness flushes caches
// between replays anyway). Unroll-2: 8 vector loads in flight per wave.
__global__ __launch_bounds__(256) void k_reduce(const float* __restrict__ x,
                                                const int* __restrict__ tg,
                                                float* __restrict__ pfs,
                                                float* __restrict__ pbs,
                                                unsigned* __restrict__ pfc,
                                                uint4* __restrict__ histz,
                                                unsigned* __restrict__ flags,
                                                int have_hist) {
    const int b = blockIdx.y;
    if (b == 0 && blockIdx.x < 32) {
        if (have_hist) histz[blockIdx.x * 256 + threadIdx.x] = make_uint4(0u, 0u, 0u, 0u);
        if (blockIdx.x == 0 && threadIdx.x == 0) flags[1] = 0u;   // k_tail done-counter: reset in-call
    }
    const float* xb = x + (size_t)b * 3 * NPIX;
    const int* tb = tg + (size_t)b * NPIX;
    float fs = 0.f, bs = 0.f;
    int fc = 0;
    const int base = (blockIdx.x * 256 + threadIdx.x) * 4;
    const int stride = G1 * 256 * 4;  // pixels per grid sweep
#pragma unroll
    for (int it = 0; it < NPIX / stride; it += 2) {
        const int i0 = it * stride + base;
        const int i1 = i0 + stride;
        const vflt4 a0 = __builtin_nontemporal_load((const vflt4*)(xb + i0));
        const vflt4 c0 = __builtin_nontemporal_load((const vflt4*)(xb + NPIX + i0));
        const vflt4 d0 = __builtin_nontemporal_load((const vflt4*)(xb + 2 * NPIX + i0));
        const vint4 t0 = __builtin_nontemporal_load((const vint4*)(tb + i0));
        const vflt4 a1 = __builtin_nontemporal_load((const vflt4*)(xb + i1));
        const vflt4 c1 = __builtin_nontemporal_load((const vflt4*)(xb + NPIX + i1));
        const vflt4 d1 = __builtin_nontemporal_load((const vflt4*)(xb + 2 * NPIX + i1));
        const vint4 t1 = __builtin_nontemporal_load((const vint4*)(tb + i1));
        float l;
#pragma unroll
        for (int j = 0; j < 4; ++j) {
            l = pix_loss(a0[j], c0[j], d0[j], t0[j]);
            if (t0[j] > 0) { fs += l; fc++; } else bs += l;
        }
#pragma unroll
        for (int j = 0; j < 4; ++j) {
            l = pix_loss(a1[j], c1[j], d1[j], t1[j]);
            if (t1[j] > 0) { fs += l; fc++; } else bs += l;
        }
    }
#pragma unroll
    for (int off = 32; off > 0; off >>= 1) {
        fs += __shfl_down(fs, off);
        bs += __shfl_down(bs, off);
        fc += __shfl_down(fc, off);
    }
    __shared__ float sfs[4], sbs[4];
    __shared__ int sfc[4];
    const int wid = threadIdx.x >> 6;
    if ((threadIdx.x & 63) == 0) { sfs[wid] = fs; sbs[wid] = bs; sfc[wid] = fc; }
    __syncthreads();
    if (threadIdx.x == 0) {
        const int slot = b * G1 + blockIdx.x;
        pfs[slot] = sfs[0] + sfs[1] + sfs[2] + sfs[3];
        pbs[slot] = sbs[0] + sbs[1] + sbs[2] + sbs[3];
        pfc[slot] = (unsigned)(sfc[0] + sfc[1] + sfc[2] + sfc[3]);
    }
}

// helper: reduce one image's partial arrays (G1 slots) across the block.
// Totals broadcast to ALL threads via LDS.
__device__ __forceinline__ void reduce_image(const float* __restrict__ pfs,
                                             const float* __restrict__ pbs,
                                             const unsigned* __restrict__ pfc,
                                             int b2, int tid,
                                             double* __restrict__ sda,
                                             double* __restrict__ sdb,
                                             unsigned* __restrict__ su,
                                             double& tfs, double& tbs, u64& tfc) {
    double fs = 0.0, bs = 0.0;
    unsigned fc = 0;
    if (tid < G1 / 4) {
        const float4 f4 = ((const float4*)pfs)[b2 * (G1 / 4) + tid];
        const float4 b4 = ((const float4*)pbs)[b2 * (G1 / 4) + tid];
        const uint4 c4 = ((const uint4*)pfc)[b2 * (G1 / 4) + tid];
        fs = (double)f4.x + (double)f4.y + (double)f4.z + (double)f4.w;
        bs = (double)b4.x + (double)b4.y + (double)b4.z + (double)b4.w;
        fc = c4.x + c4.y + c4.z + c4.w;
    }
#pragma unroll
    for (int off = 32; off > 0; off >>= 1) {
        fs += __shfl_down(fs, off);
        bs += __shfl_down(bs, off);
        fc += __shfl_down(fc, off);
    }
    const int wid = tid >> 6;
    if ((tid & 63) == 0) { sda[wid] = fs; sdb[wid] = bs; su[wid] = fc; }
    __syncthreads();
    tfs = sda[0] + sda[1] + sda[2] + sda[3];
    tbs = sdb[0] + sdb[1] + sdb[2] + sdb[3];
    tfc = (u64)su[0] + su[1] + su[2] + su[3];
    __syncthreads();
}

// K2: merged tail (round-8 proven structure; reads ONLY same-call-written
// data — poison-immune). Fast path: block (0,0) computes the scalar; all
// other blocks exit after the own-image need check.
__global__ __launch_bounds__(256) void k_tail(const float* __restrict__ pfs,
                                              const float* __restrict__ pbs,
                                              const unsigned* __restrict__ pfc,
                                              const float* __restrict__ x,
                                              const int* __restrict__ tg,
                                              unsigned* __restrict__ hist_cnt,
                                              float* __restrict__ hist_sum,
                                              unsigned* __restrict__ flags,
                                              float* __restrict__ out,
                                              int have_hist) {
    const int b = blockIdx.y;
    const int tid = threadIdx.x;
    __shared__ double sda[4], sdb[4];
    __shared__ unsigned su[4];

    // own-image fg count (uniform across block)
    u64 fc_own;
    {
        unsigned s = 0;
        if (tid < G1 / 4) {
            const uint4 c4 = ((const uint4*)pfc)[b * (G1 / 4) + tid];
            s = c4.x + c4.y + c4.z + c4.w;
        }
#pragma unroll
        for (int off = 32; off > 0; off >>= 1) s += __shfl_down(s, off);
        if ((tid & 63) == 0) su[tid >> 6] = s;
        __syncthreads();
        fc_own = (u64)su[0] + su[1] + su[2] + su[3];
        __syncthreads();
    }
    const u64 bg_own = (u64)NPIX - fc_own;
    const u64 mk_own = fc_own > MINK ? fc_own : MINK;
    const u64 k_own = bg_own < mk_own ? bg_own : mk_own;
    const bool need_own = (k_own < bg_own) && have_hist;

    // block (0,0): final scalar on the no-hist path
    if (blockIdx.x == 0 && b == 0) {
        double acc = 0.0;
        bool any_need = false;
        for (int b2 = 0; b2 < BATCH; ++b2) {
            double tfs, tbs; u64 tfc;
            reduce_image(pfs, pbs, pfc, b2, tid, sda, sdb, su, tfs, tbs, tfc);
            const u64 bg = (u64)NPIX - tfc;
            const u64 mk = tfc > MINK ? tfc : MINK;
            const u64 k = bg < mk ? bg : mk;
            if (k < bg && have_hist) any_need = true;
            const double fg_term = (tfc > 0) ? tfs / (double)tfc : 0.0;
            const u64 kd = k > 1 ? k : 1;
            const double bg_term = (bg > 0) ? tbs / (double)kd : 0.0;  // valid iff k>=bg (or !have_hist)
            acc += fg_term + bg_term;
        }
        if (tid == 0 && !any_need) out[0] = (float)(acc / (double)BATCH);
    }

    if (!need_own) return;

    // ---------------- hist path (not exercised on this data) ----------------
    __shared__ unsigned hc[NBINS];
    __shared__ float hs[NBINS];
    for (int i = tid; i < NBINS; i += 256) { hc[i] = 0u; hs[i] = 0.f; }
    __syncthreads();
    {
        const float* xb = x + (size_t)b * 3 * NPIX;
        const int* tb = tg + (size_t)b * NPIX;
        const int stride = HG * 256 * 4;
        for (int i = (blockIdx.x * 256 + tid) * 4; i < NPIX; i += stride) {
            const float4 a = *(const float4*)(xb + i);
            const float4 c = *(const float4*)(xb + NPIX + i);
            const float4 d = *(const float4*)(xb + 2 * NPIX + i);
            const int4 t4 = *(const int4*)(tb + i);
            float v[4][3] = {{a.x, c.x, d.x}, {a.y, c.y, d.y}, {a.z, c.z, d.z}, {a.w, c.w, d.w}};
            int tt[4] = {t4.x, t4.y, t4.z, t4.w};
#pragma unroll
            for (int j = 0; j < 4; ++j) {
                if (tt[j] == 0) {
                    float l = fmaxf(pix_loss(v[j][0], v[j][1], v[j][2], tt[j]), 0.f);
                    unsigned bin = __float_as_uint(l) >> 20;  // monotone for x>=0
                    atomicAdd(&hc[bin], 1u);
                    atomicAdd(&hs[bin], l);
                }
            }
        }
    }
    __syncthreads();
    for (int i = tid; i < NBINS; i += 256) {
        if (hc[i]) {
            atomicAdd(&hist_cnt[(size_t)b * NBINS + i], hc[i]);
            atomicAdd(&hist_sum[(size_t)b * NBINS + i], hs[i]);
        }
    }

    // participant count = HG * (#images needing hist); computed uniformly
    int nneed = 0;
    for (int b2 = 0; b2 < BATCH; ++b2) {
        unsigned s = 0;
        if (tid < G1 / 4) {
            const uint4 c4 = ((const uint4*)pfc)[b2 * (G1 / 4) + tid];
            s = c4.x + c4.y + c4.z + c4.w;
        }
#pragma unroll
        for (int off = 32; off > 0; off >>= 1) s += __shfl_down(s, off);
        if ((tid & 63) == 0) su[tid >> 6] = s;
        __syncthreads();
        const u64 fc2 = (u64)su[0] + su[1] + su[2] + su[3];
        __syncthreads();
        const u64 bg2 = (u64)NPIX - fc2;
        const u64 mk2 = fc2 > MINK ? fc2 : MINK;
        const u64 k2 = bg2 < mk2 ? bg2 : mk2;
        if (k2 < bg2) nneed++;
    }

    __threadfence();
    __syncthreads();
    __shared__ int is_last;
    if (tid == 0) {
        unsigned v = atomicAdd(&flags[1], 1u);
        is_last = (v == (unsigned)(HG * nneed) - 1u) ? 1 : 0;
    }
    __syncthreads();
    if (!is_last) return;
    __threadfence();

    // fixup: recompute every image's terms; top-k from the global hist
    double acc = 0.0;
    for (int b2 = 0; b2 < BATCH; ++b2) {
        double tfs, tbs; u64 tfc;
        reduce_image(pfs, pbs, pfc, b2, tid, sda, sdb, su, tfs, tbs, tfc);
        const u64 bg = (u64)NPIX - tfc;
        const u64 mk = tfc > MINK ? tfc : MINK;
        const u64 k = bg < mk ? bg : mk;
        double bg_sel = tbs;
        if (k < bg) {
            for (int i = tid; i < NBINS; i += 256) {
                hc[i] = __hip_atomic_load(&hist_cnt[(size_t)b2 * NBINS + i],
                                          __ATOMIC_ACQUIRE, __HIP_MEMORY_SCOPE_AGENT);
                hs[i] = __hip_atomic_load(&hist_sum[(size_t)b2 * NBINS + i],
                                          __ATOMIC_ACQUIRE, __HIP_MEMORY_SCOPE_AGENT);
            }
            __syncthreads();
            if (tid == 0) {
                u64 cnt = 0; double s = 0.0, topk = 0.0;
                for (int i = NBINS - 1; i >= 0; --i) {
                    unsigned c = hc[i];
                    if (cnt + c >= k) {
                        double edge = (double)__uint_as_float(((unsigned)i) << 20);
                        topk = s + (double)(k - cnt) * edge;
                        break;
                    }
                    cnt += c;
                    s += (double)hs[i];
                }
                sda[0] = topk;
            }
            __syncthreads();
            bg_sel = sda[0];
            __syncthreads();
        }
        const double fg_term = (tfc > 0) ? tfs / (double)tfc : 0.0;
        const u64 kd = k > 1 ? k : 1;
        const double bg_term = (bg > 0) ? bg_sel / (double)kd : 0.0;
        acc += fg_term + bg_term;
    }
    if (tid == 0) out[0] = (float)(acc / (double)BATCH);
}

extern "C" void kernel_launch(void* const* d_in, const int* in_sizes, int n_in,
                              void* d_out, int out_size, void* d_ws, size_t ws_size,
                              hipStream_t stream) {
    const float* x = (const float*)d_in[0];
    const int* tg = (const int*)d_in[1];
    float* out = (float*)d_out;

    char* ws = (char*)d_ws;
    float* pfs = (float*)ws;                                   // 8 KB used
    float* pbs = (float*)(ws + 16384);                         // 8 KB used
    unsigned* pfc = (unsigned*)(ws + 32768);                   // 8 KB used
    unsigned* flags = (unsigned*)(ws + 49152);                 // 128 B
    unsigned* hist_cnt = (unsigned*)(ws + 49280);              // 64 KB
    float* hist_sum = (float*)(ws + 49280 + (size_t)BATCH * NBINS * 4);  // 64 KB
    uint4* histz = (uint4*)(ws + 49280);                       // cnt+sum contiguous: 8192 uint4
    const size_t need_ws = 49280 + (size_t)BATCH * NBINS * 8;
    const int have_hist = (ws_size >= need_ws) ? 1 : 0;

    dim3 block(256);
    dim3 grid1(G1, BATCH);
    k_reduce<<<grid1, block, 0, stream>>>(x, tg, pfs, pbs, pfc, histz, flags, have_hist);
    dim3 grid2(HG, BATCH);
    k_tail<<<grid2, block, 0, stream>>>(pfs, pbs, pfc, x, tg,
                                        hist_cnt, hist_sum, flags, out, have_hist);
}